// Round 3
// baseline (235.344 us; speedup 1.0000x reference)
//
#include <hip/hip_runtime.h>
#include <math.h>

#define KEHALF_F 7.199822675975274f   // 14.399645351950548 / 2
#define A_ATOMS 1024
#define ROWS_PER_BLOCK 8

__device__ __forceinline__ float softplus_f(float x) {
    return log1pf(__expf(x));
}

// One fused kernel. Grid: (B*A)/8 blocks of 256 threads.
// Each block: 8 consecutive rows (same batch). Each wave: rows wid and wid+4,
// processed interleaved for ILP. Zf/Zp table staged once per block in LDS.
__global__ __launch_bounds__(256) void zbl_fused_kernel(
    const int* __restrict__ neighbors,
    const float* __restrict__ neighbor_mask,
    const int* __restrict__ atomic_numbers,
    const float* __restrict__ r_ij,
    const float* __restrict__ p_adiv, const float* __restrict__ p_apow,
    const float* __restrict__ p_c1, const float* __restrict__ p_c2,
    const float* __restrict__ p_c3, const float* __restrict__ p_c4,
    const float* __restrict__ p_a1, const float* __restrict__ p_a2,
    const float* __restrict__ p_a3, const float* __restrict__ p_a4,
    float* __restrict__ out, int K)
{
    __shared__ float2 zz[A_ATOMS];   // (.x = Zf, .y = Zf^sp(apow)) for this batch

    // softplus'd params — uniform, computed once per thread (cheap vs K-loop)
    const float sp_apow = softplus_f(p_apow[0]);
    const float sp_adiv = softplus_f(p_adiv[0]);
    float c1 = softplus_f(p_c1[0]), c2 = softplus_f(p_c2[0]);
    float c3 = softplus_f(p_c3[0]), c4 = softplus_f(p_c4[0]);
    const float inv_cs = 1.0f / (c1 + c2 + c3 + c4);
    c1 *= inv_cs; c2 *= inv_cs; c3 *= inv_cs; c4 *= inv_cs;
    const float a1 = softplus_f(p_a1[0]), a2 = softplus_f(p_a2[0]);
    const float a3 = softplus_f(p_a3[0]), a4 = softplus_f(p_a4[0]);

    const int row_base = blockIdx.x * ROWS_PER_BLOCK;
    const int b = row_base >> 10;                       // A_ATOMS == 1024
    const int* z_row = atomic_numbers + (b << 10);

    // Stage Zf and recompute Zp in-register (only 4 KB of global reads/block)
    for (int t = threadIdx.x; t < A_ATOMS; t += 256) {
        float zf = (float)z_row[t];
        float zp = __expf(sp_apow * __logf(zf));        // zf >= 1
        zz[t] = make_float2(zf, zp);
    }
    __syncthreads();

    const int wid  = threadIdx.x >> 6;
    const int lane = threadIdx.x & 63;

    const int row0 = row_base + wid;
    const int row1 = row_base + wid + 4;
    const float2 zi0 = zz[row0 & (A_ATOMS - 1)];
    const float2 zi1 = zz[row1 & (A_ATOMS - 1)];

    const size_t base0 = (size_t)row0 * K;
    const size_t base1 = (size_t)row1 * K;
    const int*   nb0 = neighbors     + base0;
    const float* mk0 = neighbor_mask + base0;
    const float* rr0 = r_ij          + base0;
    const int*   nb1 = neighbors     + base1;
    const float* mk1 = neighbor_mask + base1;
    const float* rr1 = r_ij          + base1;

    float acc0 = 0.0f, acc1 = 0.0f;
    const int niter = (K + 63) >> 6;                    // 16 for K=1023
    #pragma unroll 4
    for (int it = 0; it < niter; ++it) {
        const int k = (it << 6) + lane;
        if (k < K) {
            // row 0
            int   j0 = nb0[k];
            float m0 = mk0[k];
            float r0 = rr0[k];
            float2 zj0 = zz[j0];
            float ar0 = (zi0.y + zj0.y) * sp_adiv * m0 * r0;
            float f0  = c1 * __expf(-a1 * ar0) + c2 * __expf(-a2 * ar0)
                      + c3 * __expf(-a3 * ar0) + c4 * __expf(-a4 * ar0);
            acc0 += f0 * __fdividef(zi0.x * zj0.x * m0, r0);
            // row 1 (independent chain)
            int   j1 = nb1[k];
            float m1 = mk1[k];
            float r1 = rr1[k];
            float2 zj1 = zz[j1];
            float ar1 = (zi1.y + zj1.y) * sp_adiv * m1 * r1;
            float f1  = c1 * __expf(-a1 * ar1) + c2 * __expf(-a2 * ar1)
                      + c3 * __expf(-a3 * ar1) + c4 * __expf(-a4 * ar1);
            acc1 += f1 * __fdividef(zi1.x * zj1.x * m1, r1);
        }
    }

    // wave-level reduction only (no cross-wave LDS pass, no extra barrier)
    #pragma unroll
    for (int off = 32; off > 0; off >>= 1) {
        acc0 += __shfl_down(acc0, off, 64);
        acc1 += __shfl_down(acc1, off, 64);
    }
    if (lane == 0) {
        out[row0] = KEHALF_F * acc0;
        out[row1] = KEHALF_F * acc1;
    }
}

extern "C" void kernel_launch(void* const* d_in, const int* in_sizes, int n_in,
                              void* d_out, int out_size, void* d_ws, size_t ws_size,
                              hipStream_t stream) {
    const int*   neighbors      = (const int*)  d_in[0];
    const float* neighbor_mask  = (const float*)d_in[1];
    const int*   atomic_numbers = (const int*)  d_in[2];
    const float* r_ij           = (const float*)d_in[3];

    float* out = (float*)d_out;

    const int n = in_sizes[2];          // B*A = 16384
    const int K = in_sizes[0] / n;      // 1023

    zbl_fused_kernel<<<n / ROWS_PER_BLOCK, 256, 0, stream>>>(
        neighbors, neighbor_mask, atomic_numbers, r_ij,
        (const float*)d_in[4], (const float*)d_in[5],
        (const float*)d_in[6], (const float*)d_in[7],
        (const float*)d_in[8], (const float*)d_in[9],
        (const float*)d_in[10], (const float*)d_in[11],
        (const float*)d_in[12], (const float*)d_in[13],
        out, K);
}

// Round 5
// 222.139 us; speedup vs baseline: 1.0594x; 1.0594x over previous
//
#include <hip/hip_runtime.h>
#include <math.h>

#define KEHALF_F 7.199822675975274f   // 14.399645351950548 / 2
#define A_ATOMS 1024
#define LOG2E_F 1.4426950408889634f

__device__ __forceinline__ float softplus_f(float x) {
    return log1pf(__expf(x));
}

// One row per wave, 4 rows per 256-thread block -> 4096 blocks (high TLP).
// Vectorized int4/float4 streaming loads with per-row 16B alignment fixup.
__global__ __launch_bounds__(256) void zbl_fused_kernel(
    const int* __restrict__ neighbors,
    const float* __restrict__ neighbor_mask,
    const int* __restrict__ atomic_numbers,
    const float* __restrict__ r_ij,
    const float* __restrict__ p_adiv, const float* __restrict__ p_apow,
    const float* __restrict__ p_c1, const float* __restrict__ p_c2,
    const float* __restrict__ p_c3, const float* __restrict__ p_c4,
    const float* __restrict__ p_a1, const float* __restrict__ p_a2,
    const float* __restrict__ p_a3, const float* __restrict__ p_a4,
    float* __restrict__ out, int K)
{
    __shared__ float2 zz[A_ATOMS];   // .x = Zf, .y = Zf^sp(apow) * sp(adiv)

    // uniform params, once per thread
    const float sp_apow = softplus_f(p_apow[0]);
    const float sp_adiv = softplus_f(p_adiv[0]);
    float c1 = softplus_f(p_c1[0]), c2 = softplus_f(p_c2[0]);
    float c3 = softplus_f(p_c3[0]), c4 = softplus_f(p_c4[0]);
    const float inv_cs = 1.0f / (c1 + c2 + c3 + c4);
    c1 *= inv_cs; c2 *= inv_cs; c3 *= inv_cs; c4 *= inv_cs;
    const float b1 = -softplus_f(p_a1[0]) * LOG2E_F;
    const float b2 = -softplus_f(p_a2[0]) * LOG2E_F;
    const float b3 = -softplus_f(p_a3[0]) * LOG2E_F;
    const float b4 = -softplus_f(p_a4[0]) * LOG2E_F;

    const int row_base = blockIdx.x << 2;          // 4 rows per block
    const int b = row_base >> 10;                  // A_ATOMS == 1024
    const int* zrow = atomic_numbers + (b << 10);

    for (int t = threadIdx.x; t < A_ATOMS; t += 256) {
        float zf = (float)zrow[t];
        float zp = exp2f(sp_apow * log2f(zf)) * sp_adiv;  // zf >= 1
        zz[t] = make_float2(zf, zp);
    }
    __syncthreads();

    const int wid  = threadIdx.x >> 6;
    const int lane = threadIdx.x & 63;
    const int row  = row_base + wid;

    const float2 zi = zz[row & (A_ATOMS - 1)];
    const float zix = KEHALF_F * zi.x;             // fold final scale
    const float ziy = zi.y;

    const size_t base = (size_t)row * K;
    // front scalars needed to reach 16B alignment (in elements)
    const int f = (int)((4 - (int)(base & 3)) & 3);
    const int ngroups = (K - f) >> 2;              // aligned vec4 groups
    const int tailc   = (K - f) & 3;

    const int*   nb = neighbors     + base;
    const float* mk = neighbor_mask + base;
    const float* rr = r_ij          + base;
    const int4*   nb4 = (const int4*)  (nb + f);
    const float4* mk4 = (const float4*)(mk + f);
    const float4* rr4 = (const float4*)(rr + f);

    float acc = 0.0f;

#define ZBL_TERM(J, M, R)                                                   \
    {                                                                       \
        float2 zj = zz[(J)];                                                \
        float ar = (ziy + zj.y) * (M) * (R);                                \
        float fe = c1 * exp2f(b1 * ar) + c2 * exp2f(b2 * ar)                \
                 + c3 * exp2f(b3 * ar) + c4 * exp2f(b4 * ar);               \
        acc += fe * __fdividef(zix * zj.x * (M), (R));                      \
    }

    #pragma unroll 2
    for (int g = lane; g < ngroups; g += 64) {
        int4   j4 = nb4[g];
        float4 m4 = mk4[g];
        float4 r4 = rr4[g];
        ZBL_TERM(j4.x, m4.x, r4.x);
        ZBL_TERM(j4.y, m4.y, r4.y);
        ZBL_TERM(j4.z, m4.z, r4.z);
        ZBL_TERM(j4.w, m4.w, r4.w);
    }

    // <=3 front + <=3 tail scalar elements, handled by the first few lanes
    int e = -1;
    if (lane < f)                 e = lane;                            // front
    else if (lane - f < tailc)    e = f + (ngroups << 2) + (lane - f); // tail
    if (e >= 0) {
        int   j = nb[e];
        float m = mk[e];
        float r = rr[e];
        ZBL_TERM(j, m, r);
    }
#undef ZBL_TERM

    // wave-level reduction
    #pragma unroll
    for (int off = 32; off > 0; off >>= 1)
        acc += __shfl_down(acc, off, 64);
    if (lane == 0)
        out[row] = acc;
}

extern "C" void kernel_launch(void* const* d_in, const int* in_sizes, int n_in,
                              void* d_out, int out_size, void* d_ws, size_t ws_size,
                              hipStream_t stream) {
    const int*   neighbors      = (const int*)  d_in[0];
    const float* neighbor_mask  = (const float*)d_in[1];
    const int*   atomic_numbers = (const int*)  d_in[2];
    const float* r_ij           = (const float*)d_in[3];

    float* out = (float*)d_out;

    const int n = in_sizes[2];          // B*A = 16384
    const int K = in_sizes[0] / n;      // 1023

    zbl_fused_kernel<<<n / 4, 256, 0, stream>>>(
        neighbors, neighbor_mask, atomic_numbers, r_ij,
        (const float*)d_in[4], (const float*)d_in[5],
        (const float*)d_in[6], (const float*)d_in[7],
        (const float*)d_in[8], (const float*)d_in[9],
        (const float*)d_in[10], (const float*)d_in[11],
        (const float*)d_in[12], (const float*)d_in[13],
        out, K);
}

// Round 6
// 216.155 us; speedup vs baseline: 1.0888x; 1.0277x over previous
//
#include <hip/hip_runtime.h>
#include <math.h>

#define KEHALF_F 7.199822675975274f   // 14.399645351950548 / 2
#define A_ATOMS 1024
#define LOG2E_F 1.4426950408889634f
#define LN2_F   0.6931471805599453f

#if !__has_builtin(__builtin_amdgcn_exp2f)
extern "C" __device__ float __ocml_native_exp2_f32(float);
#endif
#if !__has_builtin(__builtin_amdgcn_logf)
extern "C" __device__ float __ocml_native_log2_f32(float);
#endif

__device__ __forceinline__ float fast_exp2(float x) {   // v_exp_f32 (2^x)
#if __has_builtin(__builtin_amdgcn_exp2f)
    return __builtin_amdgcn_exp2f(x);
#else
    return __ocml_native_exp2_f32(x);
#endif
}
__device__ __forceinline__ float fast_log2(float x) {   // v_log_f32 (log2 x)
#if __has_builtin(__builtin_amdgcn_logf)
    return __builtin_amdgcn_logf(x);
#else
    return __ocml_native_log2_f32(x);
#endif
}
// softplus(x) = ln(1+e^x) = ln2 * log2(1 + 2^(x*log2e)) — native-op version
__device__ __forceinline__ float softplus_f(float x) {
    return LN2_F * fast_log2(1.0f + fast_exp2(x * LOG2E_F));
}

// One row per wave, 4 rows per 256-thread block -> 4096 blocks.
// All 12 vec4 loads of a row issued up front (576 B/lane in flight).
__global__ __launch_bounds__(256) void zbl_fused_kernel(
    const int* __restrict__ neighbors,
    const float* __restrict__ neighbor_mask,
    const int* __restrict__ atomic_numbers,
    const float* __restrict__ r_ij,
    const float* __restrict__ p_adiv, const float* __restrict__ p_apow,
    const float* __restrict__ p_c1, const float* __restrict__ p_c2,
    const float* __restrict__ p_c3, const float* __restrict__ p_c4,
    const float* __restrict__ p_a1, const float* __restrict__ p_a2,
    const float* __restrict__ p_a3, const float* __restrict__ p_a4,
    float* __restrict__ out, int K)
{
    __shared__ float2 zz[A_ATOMS];   // .x = Zf, .y = Zf^sp(apow) * sp(adiv)

    const float sp_apow = softplus_f(p_apow[0]);
    const float sp_adiv = softplus_f(p_adiv[0]);
    float c1 = softplus_f(p_c1[0]), c2 = softplus_f(p_c2[0]);
    float c3 = softplus_f(p_c3[0]), c4 = softplus_f(p_c4[0]);
    const float inv_cs = 1.0f / (c1 + c2 + c3 + c4);
    c1 *= inv_cs; c2 *= inv_cs; c3 *= inv_cs; c4 *= inv_cs;
    const float b1 = -softplus_f(p_a1[0]) * LOG2E_F;
    const float b2 = -softplus_f(p_a2[0]) * LOG2E_F;
    const float b3 = -softplus_f(p_a3[0]) * LOG2E_F;
    const float b4 = -softplus_f(p_a4[0]) * LOG2E_F;

    const int row_base = blockIdx.x << 2;          // 4 rows per block
    const int b = row_base >> 10;                  // A_ATOMS == 1024
    const int* zrow = atomic_numbers + (b << 10);

    for (int t = threadIdx.x; t < A_ATOMS; t += 256) {
        float zf = (float)zrow[t];
        float zp = fast_exp2(sp_apow * fast_log2(zf)) * sp_adiv;  // zf >= 1
        zz[t] = make_float2(zf, zp);
    }
    __syncthreads();

    const int wid  = threadIdx.x >> 6;
    const int lane = threadIdx.x & 63;
    const int row  = row_base + wid;

    const float2 zi = zz[row & (A_ATOMS - 1)];
    const float zix = KEHALF_F * zi.x;             // fold final scale
    const float ziy = zi.y;

    const size_t base = (size_t)row * K;
    const int f = (int)((4 - (int)(base & 3)) & 3);   // front scalars to align
    const int ngroups = (K - f) >> 2;                 // 255 for K=1023
    const int tailc   = (K - f) & 3;

    const int*   nb = neighbors     + base;
    const float* mk = neighbor_mask + base;
    const float* rr = r_ij          + base;
    const int4*   nb4 = (const int4*)  (nb + f);
    const float4* mk4 = (const float4*)(mk + f);
    const float4* rr4 = (const float4*)(rr + f);

    float acc = 0.0f;

#define ZBL_TERM(J, M, R)                                                   \
    {                                                                       \
        float2 zj = zz[(J)];                                                \
        float ar = (ziy + zj.y) * (M) * (R);                                \
        float fe = c1 * fast_exp2(b1 * ar) + c2 * fast_exp2(b2 * ar)        \
                 + c3 * fast_exp2(b3 * ar) + c4 * fast_exp2(b4 * ar);       \
        acc += fe * __fdividef(zix * zj.x * (M), (R));                      \
    }

    // groups 0..2 always valid for K>=259; group 3 clamped + masked
    const int g0 = lane, g1 = lane + 64, g2 = lane + 128, g3 = lane + 192;
    const int g3c   = g3 < ngroups ? g3 : (ngroups - 1);
    const float w3  = g3 < ngroups ? 1.0f : 0.0f;

    int4   j0 = nb4[g0], j1 = nb4[g1], j2 = nb4[g2], j3 = nb4[g3c];
    float4 m0 = mk4[g0], m1 = mk4[g1], m2 = mk4[g2], m3 = mk4[g3c];
    float4 r0 = rr4[g0], r1 = rr4[g1], r2 = rr4[g2], r3 = rr4[g3c];
    m3.x *= w3; m3.y *= w3; m3.z *= w3; m3.w *= w3;

    ZBL_TERM(j0.x, m0.x, r0.x); ZBL_TERM(j0.y, m0.y, r0.y);
    ZBL_TERM(j0.z, m0.z, r0.z); ZBL_TERM(j0.w, m0.w, r0.w);
    ZBL_TERM(j1.x, m1.x, r1.x); ZBL_TERM(j1.y, m1.y, r1.y);
    ZBL_TERM(j1.z, m1.z, r1.z); ZBL_TERM(j1.w, m1.w, r1.w);
    ZBL_TERM(j2.x, m2.x, r2.x); ZBL_TERM(j2.y, m2.y, r2.y);
    ZBL_TERM(j2.z, m2.z, r2.z); ZBL_TERM(j2.w, m2.w, r2.w);
    ZBL_TERM(j3.x, m3.x, r3.x); ZBL_TERM(j3.y, m3.y, r3.y);
    ZBL_TERM(j3.z, m3.z, r3.z); ZBL_TERM(j3.w, m3.w, r3.w);

    // <=3 front + tail scalar elements, handled by the first few lanes
    int e = -1;
    if (lane < f)                 e = lane;                            // front
    else if (lane - f < tailc)    e = f + (ngroups << 2) + (lane - f); // tail
    if (e >= 0) {
        int   j = nb[e];
        float m = mk[e];
        float r = rr[e];
        ZBL_TERM(j, m, r);
    }
#undef ZBL_TERM

    #pragma unroll
    for (int off = 32; off > 0; off >>= 1)
        acc += __shfl_down(acc, off, 64);
    if (lane == 0)
        out[row] = acc;
}

extern "C" void kernel_launch(void* const* d_in, const int* in_sizes, int n_in,
                              void* d_out, int out_size, void* d_ws, size_t ws_size,
                              hipStream_t stream) {
    const int*   neighbors      = (const int*)  d_in[0];
    const float* neighbor_mask  = (const float*)d_in[1];
    const int*   atomic_numbers = (const int*)  d_in[2];
    const float* r_ij           = (const float*)d_in[3];

    float* out = (float*)d_out;

    const int n = in_sizes[2];          // B*A = 16384
    const int K = in_sizes[0] / n;      // 1023

    zbl_fused_kernel<<<n / 4, 256, 0, stream>>>(
        neighbors, neighbor_mask, atomic_numbers, r_ij,
        (const float*)d_in[4], (const float*)d_in[5],
        (const float*)d_in[6], (const float*)d_in[7],
        (const float*)d_in[8], (const float*)d_in[9],
        (const float*)d_in[10], (const float*)d_in[11],
        (const float*)d_in[12], (const float*)d_in[13],
        out, K);
}